// Round 8
// baseline (459.982 us; speedup 1.0000x reference)
//
#include <hip/hip_runtime.h>

typedef unsigned short u16;
typedef unsigned int u32;
typedef short v8s __attribute__((ext_vector_type(8)));
typedef float v4f __attribute__((ext_vector_type(4)));

#define MFMA16(a, b, c) __builtin_amdgcn_mfma_f32_16x16x32_bf16(a, b, c, 0, 0, 0)

__device__ __forceinline__ u16 f2bf(float f) {
  u32 u = __float_as_uint(f);
  u32 r = (u + 0x7fffu + ((u >> 16) & 1u)) >> 16;
  return (u16)r;
}
__device__ __forceinline__ float bf2f(u16 s) {
  return __uint_as_float(((u32)s) << 16);
}

// ---------------------------------------------------------------------------
// fused f32 -> bf16 convert of the three weight matrices
__global__ __launch_bounds__(256) void cvt3(const float* __restrict__ a, u16* __restrict__ oa,
                                            int na, const float* __restrict__ b,
                                            u16* __restrict__ ob, int nb,
                                            const float* __restrict__ c, u16* __restrict__ oc,
                                            int nc) {
  int total = na + nb + nc;
  for (int i = blockIdx.x * 256 + threadIdx.x; i < total; i += gridDim.x * 256) {
    if (i < na) oa[i] = f2bf(a[i]);
    else if (i < na + nb) ob[i - na] = f2bf(b[i - na]);
    else oc[i - na - nb] = f2bf(c[i - na - nb]);
  }
}

// ---------------------------------------------------------------------------
// fused depthwise conv 3x3 + 5x5 + 7x7 (stride 1, same padding), one WG per (b,c)
__global__ __launch_bounds__(256) void conv_kernel(
    const float* __restrict__ y, const float* __restrict__ w1, const float* __restrict__ b1,
    const float* __restrict__ w2, const float* __restrict__ b2,
    const float* __restrict__ w3, const float* __restrict__ b3, float* __restrict__ yf) {
  __shared__ float img[38 * 40];
  __shared__ float wl[84];
  int blk = blockIdx.x;           // b*512 + c
  int c = blk & 511;
  int t = threadIdx.x;
  const float* ybase = &y[(size_t)blk * 1024];
  for (int idx = t; idx < 38 * 40; idx += 256) {
    int row = idx / 40, col = idx - row * 40;
    float v = 0.f;
    int gh = row - 3, gw = col - 3;
    if (col < 38 && gh >= 0 && gh < 32 && gw >= 0 && gw < 32) v = ybase[gh * 32 + gw];
    if (col < 38) img[idx] = v;
  }
  if (t < 49) wl[t] = w3[c * 49 + t];
  else if (t < 74) wl[t] = w2[c * 25 + (t - 49)];
  else if (t < 83) wl[t] = w1[c * 9 + (t - 74)];
  float bias = b1[c] + b2[c] + b3[c];
  __syncthreads();
  for (int p = t; p < 1024; p += 256) {
    int hh = p >> 5, ww = p & 31;
    float acc = bias;
#pragma unroll
    for (int i = 0; i < 7; i++)
#pragma unroll
      for (int j = 0; j < 7; j++)
        acc += img[(hh + i) * 40 + ww + j] * wl[i * 7 + j];
#pragma unroll
    for (int i = 0; i < 5; i++)
#pragma unroll
      for (int j = 0; j < 5; j++)
        acc += img[(hh + 1 + i) * 40 + ww + 1 + j] * wl[49 + i * 5 + j];
#pragma unroll
    for (int i = 0; i < 3; i++)
#pragma unroll
      for (int j = 0; j < 3; j++)
        acc += img[(hh + 2 + i) * 40 + ww + 2 + j] * wl[74 + i * 3 + j];
    yf[(size_t)blk * 1024 + p] = acc;
  }
}

// ---------------------------------------------------------------------------
// LayerNorm over C=512 for 16 pixels per WG; yf [B,C,N] f32 -> yn [B*N, C] bf16
__global__ __launch_bounds__(256) void ln_kernel(const float* __restrict__ yf,
                                                 const float* __restrict__ lnw,
                                                 const float* __restrict__ lnb,
                                                 u16* __restrict__ ynbf) {
  __shared__ float T[512][17];
  __shared__ float ps1[16][16], ps2[16][16];
  __shared__ float mu_s[16], rs_s[16];
  int blk = blockIdx.x;  // b*64 + n-group
  int b = blk >> 6;
  int n0 = (blk & 63) << 4;
  int t = threadIdx.x;
  for (int idx = t; idx < 8192; idx += 256) {
    int c = idx >> 4, j = idx & 15;
    T[c][j] = yf[((size_t)(b * 512 + c)) * 1024 + n0 + j];
  }
  __syncthreads();
  {
    int j = t & 15, part = t >> 4;
    float s1 = 0.f, s2 = 0.f;
#pragma unroll 4
    for (int cc = 0; cc < 32; cc++) {
      float v = T[part * 32 + cc][j];
      s1 += v;
      s2 += v * v;
    }
    ps1[part][j] = s1;
    ps2[part][j] = s2;
  }
  __syncthreads();
  if (t < 16) {
    float a1 = 0.f, a2 = 0.f;
#pragma unroll
    for (int p = 0; p < 16; p++) { a1 += ps1[p][t]; a2 += ps2[p][t]; }
    float mu = a1 * (1.f / 512.f);
    float var = a2 * (1.f / 512.f) - mu * mu;
    mu_s[t] = mu;
    rs_s[t] = rsqrtf(var + 1e-5f);
  }
  __syncthreads();
  for (int idx = t; idx < 8192; idx += 256) {
    int c = idx & 511, jj = idx >> 9;
    float v = (T[c][jj] - mu_s[jj]) * rs_s[jj] * lnw[c] + lnb[c];
    ynbf[((size_t)(b * 1024 + n0 + jj)) * 512 + c] = f2bf(v);
  }
}

// ---------------------------------------------------------------------------
// x [B,C,N] f32 -> xs [B*N, C] bf16 (transpose + convert)
__global__ __launch_bounds__(256) void xpose_x(const float* __restrict__ x,
                                               u16* __restrict__ xsbf) {
  __shared__ float T[32][33];
  int blk = blockIdx.x;  // ((b*16 + cb)*32 + nb)
  int nb = blk & 31, cb = (blk >> 5) & 15, b = blk >> 9;
  int c0 = cb * 32, n0 = nb * 32;
  int t = threadIdx.x;
  for (int idx = t; idx < 1024; idx += 256) {
    int ci = idx >> 5, nj = idx & 31;
    T[ci][nj] = x[((size_t)(b * 512 + c0 + ci)) * 1024 + n0 + nj];
  }
  __syncthreads();
  for (int idx = t; idx < 1024; idx += 256) {
    int nj = idx >> 5, ci = idx & 31;
    xsbf[((size_t)(b * 1024 + n0 + nj)) * 512 + c0 + ci] = f2bf(T[ci][nj]);
  }
}

// ---------------------------------------------------------------------------
// v half of kv [B*N, 1024] bf16 -> vT [B,H,64,1024] bf16
__global__ __launch_bounds__(256) void xpose_v(const u16* __restrict__ kvbf,
                                               u16* __restrict__ vT) {
  __shared__ u16 T[64][72];
  int blk = blockIdx.x;  // (b*8+h)*16 + nt
  int nt = blk & 15, bh = blk >> 4;
  int b = bh >> 3, h = bh & 7;
  int n0 = nt * 64;
  int t = threadIdx.x;
  for (int idx = t; idx < 4096; idx += 256) {
    int ni = idx >> 6, dj = idx & 63;
    T[ni][dj] = kvbf[((size_t)(b * 1024 + n0 + ni)) * 1024 + 512 + h * 64 + dj];
  }
  __syncthreads();
  for (int idx = t; idx < 4096; idx += 256) {
    int dj = idx >> 6, ni = idx & 63;
    vT[((size_t)(bh * 64 + dj)) * 1024 + n0 + ni] = T[ni][dj];
  }
}

// ---------------------------------------------------------------------------
// bf16 NT GEMM, BM=128 BN=64 BK=32, one-step register prefetch of the next
// K-tile issued before the MFMA block (hides HBM latency under compute).
__global__ __launch_bounds__(256) void gemm_nt64(const u16* __restrict__ A,
                                                 const u16* __restrict__ B,
                                                 void* __restrict__ Cout, int M, int N, int K,
                                                 int outBF) {
  __shared__ u16 As[128 * 40];
  __shared__ u16 Bs[64 * 40];
  int blk = blockIdx.x;
  int nblk = N >> 6;
  int m0 = (blk / nblk) << 7, n0 = (blk % nblk) << 6;
  int t = threadIdx.x;
  int lane = t & 63, w = t >> 6;
  int wr = w >> 1, wc = w & 1;
  int lr = lane & 15, kr = lane >> 4;

  v4f acc[4][2];
#pragma unroll
  for (int i = 0; i < 4; i++)
#pragma unroll
    for (int j = 0; j < 2; j++) acc[i][j] = (v4f){0.f, 0.f, 0.f, 0.f};

  const int r0 = t >> 2, s0 = (t & 3) * 8;
  const u16* Ap = &A[(size_t)(m0 + r0) * K + s0];
  const u16* Ap2 = &A[(size_t)(m0 + r0 + 64) * K + s0];
  const u16* Bp = &B[(size_t)(n0 + r0) * K + s0];

  int4 a0 = *(const int4*)Ap;
  int4 a1 = *(const int4*)Ap2;
  int4 b0 = *(const int4*)Bp;

  for (int k0 = 0; k0 < K; k0 += 32) {
    __syncthreads();
    *(int4*)&As[r0 * 40 + s0] = a0;
    *(int4*)&As[(r0 + 64) * 40 + s0] = a1;
    *(int4*)&Bs[r0 * 40 + s0] = b0;
    __syncthreads();
    if (k0 + 32 < K) {
      a0 = *(const int4*)(Ap + k0 + 32);
      a1 = *(const int4*)(Ap2 + k0 + 32);
      b0 = *(const int4*)(Bp + k0 + 32);
    }
    v8s af[4], bfr[2];
#pragma unroll
    for (int i = 0; i < 4; i++) af[i] = *(const v8s*)&As[(wr * 64 + i * 16 + lr) * 40 + kr * 8];
#pragma unroll
    for (int j = 0; j < 2; j++) bfr[j] = *(const v8s*)&Bs[(wc * 32 + j * 16 + lr) * 40 + kr * 8];
#pragma unroll
    for (int i = 0; i < 4; i++)
#pragma unroll
      for (int j = 0; j < 2; j++) acc[i][j] = MFMA16(af[i], bfr[j], acc[i][j]);
  }
#pragma unroll
  for (int i = 0; i < 4; i++)
#pragma unroll
    for (int j = 0; j < 2; j++) {
      int row = m0 + wr * 64 + i * 16 + kr * 4;
      int col = n0 + wc * 32 + j * 16 + lr;
#pragma unroll
      for (int q = 0; q < 4; q++) {
        float v = acc[i][j][q];
        if (outBF) ((u16*)Cout)[(size_t)(row + q) * N + col] = f2bf(v);
        else ((float*)Cout)[(size_t)(row + q) * N + col] = v;
      }
    }
}

// ---------------------------------------------------------------------------
// fused attention: per WG = (b, h, 16 q-rows).
//   Phase 1: S^T = (K q^T)/8 via swapped MFMA -> packed bf16 LDS rows.
//   Phase 2: 8 interleaved ballot binary searches (4 rows x 2 k's, 16 serial
//            steps total, no LDS/atomics); no max-shift (|s|<~2 so exp safe);
//            masked softmax weights written in-place.
//   Phase 3: PV with per-wave d-slice (no cross-wave reduce, no opart LDS).
// LDS = Sb only (33.3 KB) -> 4 WGs/CU.
__global__ __launch_bounds__(256) void attn_kernel(
    const u16* __restrict__ qbf, const u16* __restrict__ kvbf, const u16* __restrict__ vT,
    u16* __restrict__ aobf, const float* __restrict__ kr1p, const float* __restrict__ kr2p) {
  __shared__ u16 Sb[16][1032];

  int blk = blockIdx.x;
  int xq = blk & 7, jq = blk >> 3;
  int bh = xq * 8 + (jq & 7);
  int rb = jq >> 3;
  int b = bh >> 3, h = bh & 7;
  int n0 = rb * 16;
  int t = threadIdx.x, lane = t & 63, w = t >> 6;
  int lr = lane & 15, kr = lane >> 4;

  float sg1 = 1.f / (1.f + __expf(-kr1p[0]));
  int k1 = min(max((int)(1024.f * sg1), 1), 1024);
  float sg2 = 1.f / (1.f + __expf(-kr2p[0]));
  int k2 = min(max((int)(1024.f * sg2), 1), 1024);

  {  // Phase 1: S^T tiles via mfma(K, Q); q fragments straight from global.
    const u16* qp = &qbf[(size_t)(b * 1024 + n0 + lr) * 512 + h * 64];
    v8s qf0 = *(const v8s*)&qp[kr * 8];
    v8s qf1 = *(const v8s*)&qp[32 + kr * 8];
    int cbase = w * 256;
#pragma unroll
    for (int cf = 0; cf < 16; cf++) {
      int c0 = cbase + cf * 16;
      const u16* kp = &kvbf[(size_t)(b * 1024 + c0 + lr) * 1024 + h * 64];
      v8s kf0 = *(const v8s*)&kp[kr * 8];
      v8s kf1 = *(const v8s*)&kp[32 + kr * 8];
      v4f acc = (v4f){0.f, 0.f, 0.f, 0.f};
      acc = MFMA16(kf0, qf0, acc);
      acc = MFMA16(kf1, qf1, acc);
      u32 p0 = (__float_as_uint(acc[0] * 0.125f) >> 16) |
               (__float_as_uint(acc[1] * 0.125f) & 0xffff0000u);
      u32 p1 = (__float_as_uint(acc[2] * 0.125f) >> 16) |
               (__float_as_uint(acc[3] * 0.125f) & 0xffff0000u);
      *(uint2*)&Sb[lr][c0 + kr * 4] = make_uint2(p0, p1);
    }
  }
  __syncthreads();

  {  // Phase 2
    int l = lane;
    // build keys for all 4 rows (monotone u16 map of bf16 scores)
    u32 key[4][16];
#pragma unroll
    for (int i = 0; i < 4; i++) {
      const u16* rowp = &Sb[w * 4 + i][l * 16];
      uint4 r0 = *(const uint4*)rowp;
      uint4 r1 = *(const uint4*)(rowp + 8);
      u32 wdl[8] = {r0.x, r0.y, r0.z, r0.w, r1.x, r1.y, r1.z, r1.w};
#pragma unroll
      for (int p = 0; p < 8; p++) {
        u32 m = (wdl[p] >> 15) & 0x10001u;
        u32 kp = wdl[p] ^ (0x80008000u ^ (m * 0x7fffu));
        key[i][2 * p] = kp & 0xffffu;
        key[i][2 * p + 1] = kp >> 16;
      }
    }
    // 8 interleaved binary searches: largest thr with count(key >= thr) >= k
    u32 lo[8], hi[8];
#pragma unroll
    for (int q = 0; q < 8; q++) { lo[q] = 0; hi[q] = 65536; }
#pragma unroll 1
    for (int it = 0; it < 16; ++it) {
      u32 mm[8];
      int cnt[8];
#pragma unroll
      for (int q = 0; q < 8; q++) { mm[q] = (lo[q] + hi[q]) >> 1; cnt[q] = 0; }
#pragma unroll
      for (int jj = 0; jj < 16; jj++)
#pragma unroll
        for (int i = 0; i < 4; i++) {
          cnt[2 * i] += (int)__popcll(__ballot(key[i][jj] >= mm[2 * i]));
          cnt[2 * i + 1] += (int)__popcll(__ballot(key[i][jj] >= mm[2 * i + 1]));
        }
#pragma unroll
      for (int i = 0; i < 4; i++) {
        if (cnt[2 * i] >= k1) lo[2 * i] = mm[2 * i]; else hi[2 * i] = mm[2 * i];
        if (cnt[2 * i + 1] >= k2) lo[2 * i + 1] = mm[2 * i + 1]; else hi[2 * i + 1] = mm[2 * i + 1];
      }
    }
    // thresholds back to float score space
    float thrf[8];
#pragma unroll
    for (int q = 0; q < 8; q++) {
      u32 kk = lo[q];
      u16 sb = (kk & 0x8000u) ? (u16)(kk & 0x7fffu) : (u16)(~kk);
      thrf[q] = bf2f(sb);
    }
    // weights: two rows interleaved; re-read scores from LDS (keys freed)
#pragma unroll 1
    for (int i = 0; i < 4; i += 2) {
      int rrA = w * 4 + i, rrB = rrA + 1;
      float tA1 = thrf[2 * i], tA2 = thrf[2 * i + 1];
      float tB1 = thrf[2 * i + 2], tB2 = thrf[2 * i + 3];
      const u16* rpA = &Sb[rrA][l * 16];
      const u16* rpB = &Sb[rrB][l * 16];
      uint4 a0 = *(const uint4*)rpA, a1 = *(const uint4*)(rpA + 8);
      uint4 b0 = *(const uint4*)rpB, b1 = *(const uint4*)(rpB + 8);
      u32 wdA[8] = {a0.x, a0.y, a0.z, a0.w, a1.x, a1.y, a1.z, a1.w};
      u32 wdB[8] = {b0.x, b0.y, b0.z, b0.w, b1.x, b1.y, b1.z, b1.w};
      float evA[16], evB[16], sA[16], sB[16];
      float zA1 = 0.f, zA2 = 0.f, zB1 = 0.f, zB2 = 0.f;
#pragma unroll
      for (int jj = 0; jj < 16; jj++) {
        sA[jj] = bf2f((u16)(wdA[jj >> 1] >> ((jj & 1) * 16)));
        sB[jj] = bf2f((u16)(wdB[jj >> 1] >> ((jj & 1) * 16)));
        evA[jj] = __expf(sA[jj]);
        evB[jj] = __expf(sB[jj]);
        zA1 += (sA[jj] >= tA1) ? evA[jj] : 0.f;
        zA2 += (sA[jj] >= tA2) ? evA[jj] : 0.f;
        zB1 += (sB[jj] >= tB1) ? evB[jj] : 0.f;
        zB2 += (sB[jj] >= tB2) ? evB[jj] : 0.f;
      }
#pragma unroll
      for (int d = 1; d < 64; d <<= 1) {
        zA1 += __shfl_xor(zA1, d);
        zA2 += __shfl_xor(zA2, d);
        zB1 += __shfl_xor(zB1, d);
        zB2 += __shfl_xor(zB2, d);
      }
      float cA1 = 0.6f / zA1, cA2 = 0.4f / zA2;
      float cB1 = 0.6f / zB1, cB2 = 0.4f / zB2;
      u32 owA[8], owB[8];
#pragma unroll
      for (int p = 0; p < 8; p++) {
        float a0f = ((sA[2 * p] >= tA1) ? cA1 : 0.f) + ((sA[2 * p] >= tA2) ? cA2 : 0.f);
        float a1f = ((sA[2 * p + 1] >= tA1) ? cA1 : 0.f) + ((sA[2 * p + 1] >= tA2) ? cA2 : 0.f);
        float b0f = ((sB[2 * p] >= tB1) ? cB1 : 0.f) + ((sB[2 * p] >= tB2) ? cB2 : 0.f);
        float b1f = ((sB[2 * p + 1] >= tB1) ? cB1 : 0.f) + ((sB[2 * p + 1] >= tB2) ? cB2 : 0.f);
        u32 wA0 = __float_as_uint(evA[2 * p] * a0f);
        u32 wA1 = __float_as_uint(evA[2 * p + 1] * a1f);
        u32 wB0 = __float_as_uint(evB[2 * p] * b0f);
        u32 wB1 = __float_as_uint(evB[2 * p + 1] * b1f);
        owA[p] = (wA0 >> 16) | (wA1 & 0xffff0000u);
        owB[p] = (wB0 >> 16) | (wB1 & 0xffff0000u);
      }
      *(uint4*)&Sb[rrA][l * 16] = make_uint4(owA[0], owA[1], owA[2], owA[3]);
      *(uint4*)&Sb[rrA][l * 16 + 8] = make_uint4(owA[4], owA[5], owA[6], owA[7]);
      *(uint4*)&Sb[rrB][l * 16] = make_uint4(owB[0], owB[1], owB[2], owB[3]);
      *(uint4*)&Sb[rrB][l * 16 + 8] = make_uint4(owB[4], owB[5], owB[6], owB[7]);
    }
  }
  __syncthreads();

  {  // Phase 3: PV, wave w owns d-slice [w*16, w*16+16) over the full context
    const u16* vrow = &vT[(size_t)(bh * 64 + w * 16 + lr) * 1024];
    v4f acc = (v4f){0.f, 0.f, 0.f, 0.f};
#pragma unroll
    for (int ks = 0; ks < 32; ks++) {
      int c0 = ks * 32;
      v8s a = *(const v8s*)&Sb[lr][c0 + kr * 8];
      v8s bb = *(const v8s*)&vrow[c0 + kr * 8];
      acc = MFMA16(a, bb, acc);
    }
#pragma unroll
    for (int j = 0; j < 4; j++)
      aobf[(size_t)(b * 1024 + n0 + kr * 4 + j) * 512 + h * 64 + w * 16 + lr] = f2bf(acc[j]);
  }
}

// ---------------------------------------------------------------------------
// final: out[b,c,n] = proj_gemm[(b,n),c] + proj_b[c] + x[b,c,n]
__global__ __launch_bounds__(256) void xpose_out(const float* __restrict__ G,
                                                 const float* __restrict__ x,
                                                 const float* __restrict__ pb,
                                                 float* __restrict__ out) {
  __shared__ float T[32][33];
  int blk = blockIdx.x;  // ((b*16 + cb)*32 + nb)
  int nb = blk & 31, cb = (blk >> 5) & 15, b = blk >> 9;
  int c0 = cb * 32, n0 = nb * 32;
  int t = threadIdx.x;
  for (int idx = t; idx < 1024; idx += 256) {
    int nj = idx >> 5, ci = idx & 31;
    T[ci][nj] = G[((size_t)(b * 1024 + n0 + nj)) * 512 + c0 + ci];
  }
  __syncthreads();
  for (int idx = t; idx < 1024; idx += 256) {
    int ci = idx >> 5, nj = idx & 31;
    size_t o = ((size_t)(b * 512 + c0 + ci)) * 1024 + n0 + nj;
    out[o] = T[ci][nj] + pb[c0 + ci] + x[o];
  }
}

// ---------------------------------------------------------------------------
extern "C" void kernel_launch(void* const* d_in, const int* in_sizes, int n_in,
                              void* d_out, int out_size, void* d_ws, size_t ws_size,
                              hipStream_t stream) {
  (void)in_sizes; (void)n_in; (void)out_size; (void)ws_size;
  const float* x = (const float*)d_in[0];
  const float* y = (const float*)d_in[1];
  const float* q_w = (const float*)d_in[2];
  const float* kv_w = (const float*)d_in[3];
  const float* proj_w = (const float*)d_in[4];
  const float* proj_b = (const float*)d_in[5];
  const float* c1w = (const float*)d_in[6];
  const float* c1b = (const float*)d_in[7];
  const float* c2w = (const float*)d_in[8];
  const float* c2b = (const float*)d_in[9];
  const float* c3w = (const float*)d_in[10];
  const float* c3b = (const float*)d_in[11];
  const float* ln_w = (const float*)d_in[12];
  const float* ln_b = (const float*)d_in[13];
  const float* kr1 = (const float*)d_in[14];
  const float* kr2 = (const float*)d_in[15];

  char* p = (char*)d_ws;
  auto alloc = [&](size_t bytes) {
    char* q = p;
    p += (bytes + 255) & ~(size_t)255;
    return q;
  };
  float* yf = (float*)alloc(8ull * 512 * 1024 * 4);      // 16 MB [B,C,N]
  u16* ynbf = (u16*)alloc(8192ull * 512 * 2);            // 8 MB  [B*N, C]
  u16* xsbf = (u16*)alloc(8192ull * 512 * 2);            // 8 MB  [B*N, C]
  u16* qwb = (u16*)alloc(512ull * 512 * 2);
  u16* kvwb = (u16*)alloc(1024ull * 512 * 2);
  u16* pwb = (u16*)alloc(512ull * 512 * 2);
  u16* qbf = (u16*)alloc(8192ull * 512 * 2);             // 8 MB
  u16* kvbf = (u16*)alloc(8192ull * 1024 * 2);           // 16 MB
  u16* vTb = (u16*)alloc(8ull * 8 * 64 * 1024 * 2);      // 8 MB [B,H,64,N]
  u16* aobf = (u16*)alloc(8192ull * 512 * 2);            // 8 MB
  float* projf = (float*)alloc(8192ull * 512 * 4);       // 16 MB

  cvt3<<<1024, 256, 0, stream>>>(q_w, qwb, 512 * 512, kv_w, kvwb, 1024 * 512, proj_w, pwb,
                                 512 * 512);
  conv_kernel<<<8 * 512, 256, 0, stream>>>(y, c1w, c1b, c2w, c2b, c3w, c3b, yf);
  ln_kernel<<<512, 256, 0, stream>>>(yf, ln_w, ln_b, ynbf);
  xpose_x<<<8 * 16 * 32, 256, 0, stream>>>(x, xsbf);
  gemm_nt64<<<64 * 8, 256, 0, stream>>>(xsbf, qwb, qbf, 8192, 512, 512, 1);
  gemm_nt64<<<64 * 16, 256, 0, stream>>>(ynbf, kvwb, kvbf, 8192, 1024, 512, 1);
  xpose_v<<<64 * 16, 256, 0, stream>>>(kvbf, vTb);
  attn_kernel<<<64 * 64, 256, 0, stream>>>(qbf, kvbf, vTb, aobf, kr1, kr2);
  gemm_nt64<<<64 * 8, 256, 0, stream>>>(aobf, pwb, projf, 8192, 512, 512, 0);
  xpose_out<<<8 * 16 * 32, 256, 0, stream>>>(projf, x, proj_b, (float*)d_out);
}

// Round 9
// 420.081 us; speedup vs baseline: 1.0950x; 1.0950x over previous
//
#include <hip/hip_runtime.h>

typedef unsigned short u16;
typedef unsigned int u32;
typedef short v8s __attribute__((ext_vector_type(8)));
typedef float v4f __attribute__((ext_vector_type(4)));

#define MFMA16(a, b, c) __builtin_amdgcn_mfma_f32_16x16x32_bf16(a, b, c, 0, 0, 0)

__device__ __forceinline__ u16 f2bf(float f) {
  u32 u = __float_as_uint(f);
  u32 r = (u + 0x7fffu + ((u >> 16) & 1u)) >> 16;
  return (u16)r;
}
__device__ __forceinline__ float bf2f(u16 s) {
  return __uint_as_float(((u32)s) << 16);
}

// count over 64 lanes of (key >= thr) with thr scalar: v_cmp into vcc, then
// scalar popcount -> result stays in SGPR, accumulation is SALU (co-issues
// with VALU instead of burning ~5 VALU ops like __popcll(__ballot(...))).
__device__ __forceinline__ int cnt_ge(u32 key, u32 thr) {
  int r;
  asm volatile("v_cmp_le_u32 vcc, %1, %2\n\ts_bcnt1_i32_b64 %0, vcc"
               : "=s"(r)
               : "s"(thr), "v"(key)
               : "vcc");
  return r;
}

// ---------------------------------------------------------------------------
// fused f32 -> bf16 convert of the three weight matrices
__global__ __launch_bounds__(256) void cvt3(const float* __restrict__ a, u16* __restrict__ oa,
                                            int na, const float* __restrict__ b,
                                            u16* __restrict__ ob, int nb,
                                            const float* __restrict__ c, u16* __restrict__ oc,
                                            int nc) {
  int total = na + nb + nc;
  for (int i = blockIdx.x * 256 + threadIdx.x; i < total; i += gridDim.x * 256) {
    if (i < na) oa[i] = f2bf(a[i]);
    else if (i < na + nb) ob[i - na] = f2bf(b[i - na]);
    else oc[i - na - nb] = f2bf(c[i - na - nb]);
  }
}

// ---------------------------------------------------------------------------
// fused depthwise conv 3x3 + 5x5 + 7x7 (stride 1, same padding), one WG per (b,c)
__global__ __launch_bounds__(256) void conv_kernel(
    const float* __restrict__ y, const float* __restrict__ w1, const float* __restrict__ b1,
    const float* __restrict__ w2, const float* __restrict__ b2,
    const float* __restrict__ w3, const float* __restrict__ b3, float* __restrict__ yf) {
  __shared__ float img[38 * 40];
  __shared__ float wl[84];
  int blk = blockIdx.x;           // b*512 + c
  int c = blk & 511;
  int t = threadIdx.x;
  const float* ybase = &y[(size_t)blk * 1024];
  for (int idx = t; idx < 38 * 40; idx += 256) {
    int row = idx / 40, col = idx - row * 40;
    float v = 0.f;
    int gh = row - 3, gw = col - 3;
    if (col < 38 && gh >= 0 && gh < 32 && gw >= 0 && gw < 32) v = ybase[gh * 32 + gw];
    if (col < 38) img[idx] = v;
  }
  if (t < 49) wl[t] = w3[c * 49 + t];
  else if (t < 74) wl[t] = w2[c * 25 + (t - 49)];
  else if (t < 83) wl[t] = w1[c * 9 + (t - 74)];
  float bias = b1[c] + b2[c] + b3[c];
  __syncthreads();
  for (int p = t; p < 1024; p += 256) {
    int hh = p >> 5, ww = p & 31;
    float acc = bias;
#pragma unroll
    for (int i = 0; i < 7; i++)
#pragma unroll
      for (int j = 0; j < 7; j++)
        acc += img[(hh + i) * 40 + ww + j] * wl[i * 7 + j];
#pragma unroll
    for (int i = 0; i < 5; i++)
#pragma unroll
      for (int j = 0; j < 5; j++)
        acc += img[(hh + 1 + i) * 40 + ww + 1 + j] * wl[49 + i * 5 + j];
#pragma unroll
    for (int i = 0; i < 3; i++)
#pragma unroll
      for (int j = 0; j < 3; j++)
        acc += img[(hh + 2 + i) * 40 + ww + 2 + j] * wl[74 + i * 3 + j];
    yf[(size_t)blk * 1024 + p] = acc;
  }
}

// ---------------------------------------------------------------------------
// LayerNorm over C=512 for 16 pixels per WG; yf [B,C,N] f32 -> yn [B*N, C] bf16
__global__ __launch_bounds__(256) void ln_kernel(const float* __restrict__ yf,
                                                 const float* __restrict__ lnw,
                                                 const float* __restrict__ lnb,
                                                 u16* __restrict__ ynbf) {
  __shared__ float T[512][17];
  __shared__ float ps1[16][16], ps2[16][16];
  __shared__ float mu_s[16], rs_s[16];
  int blk = blockIdx.x;  // b*64 + n-group
  int b = blk >> 6;
  int n0 = (blk & 63) << 4;
  int t = threadIdx.x;
  for (int idx = t; idx < 8192; idx += 256) {
    int c = idx >> 4, j = idx & 15;
    T[c][j] = yf[((size_t)(b * 512 + c)) * 1024 + n0 + j];
  }
  __syncthreads();
  {
    int j = t & 15, part = t >> 4;
    float s1 = 0.f, s2 = 0.f;
#pragma unroll 4
    for (int cc = 0; cc < 32; cc++) {
      float v = T[part * 32 + cc][j];
      s1 += v;
      s2 += v * v;
    }
    ps1[part][j] = s1;
    ps2[part][j] = s2;
  }
  __syncthreads();
  if (t < 16) {
    float a1 = 0.f, a2 = 0.f;
#pragma unroll
    for (int p = 0; p < 16; p++) { a1 += ps1[p][t]; a2 += ps2[p][t]; }
    float mu = a1 * (1.f / 512.f);
    float var = a2 * (1.f / 512.f) - mu * mu;
    mu_s[t] = mu;
    rs_s[t] = rsqrtf(var + 1e-5f);
  }
  __syncthreads();
  for (int idx = t; idx < 8192; idx += 256) {
    int c = idx & 511, jj = idx >> 9;
    float v = (T[c][jj] - mu_s[jj]) * rs_s[jj] * lnw[c] + lnb[c];
    ynbf[((size_t)(b * 1024 + n0 + jj)) * 512 + c] = f2bf(v);
  }
}

// ---------------------------------------------------------------------------
// x [B,C,N] f32 -> xs [B*N, C] bf16 (transpose + convert)
__global__ __launch_bounds__(256) void xpose_x(const float* __restrict__ x,
                                               u16* __restrict__ xsbf) {
  __shared__ float T[32][33];
  int blk = blockIdx.x;  // ((b*16 + cb)*32 + nb)
  int nb = blk & 31, cb = (blk >> 5) & 15, b = blk >> 9;
  int c0 = cb * 32, n0 = nb * 32;
  int t = threadIdx.x;
  for (int idx = t; idx < 1024; idx += 256) {
    int ci = idx >> 5, nj = idx & 31;
    T[ci][nj] = x[((size_t)(b * 512 + c0 + ci)) * 1024 + n0 + nj];
  }
  __syncthreads();
  for (int idx = t; idx < 1024; idx += 256) {
    int nj = idx >> 5, ci = idx & 31;
    xsbf[((size_t)(b * 1024 + n0 + nj)) * 512 + c0 + ci] = f2bf(T[ci][nj]);
  }
}

// ---------------------------------------------------------------------------
// v half of kv [B*N, 1024] bf16 -> vT [B,H,64,1024] bf16
__global__ __launch_bounds__(256) void xpose_v(const u16* __restrict__ kvbf,
                                               u16* __restrict__ vT) {
  __shared__ u16 T[64][72];
  int blk = blockIdx.x;  // (b*8+h)*16 + nt
  int nt = blk & 15, bh = blk >> 4;
  int b = bh >> 3, h = bh & 7;
  int n0 = nt * 64;
  int t = threadIdx.x;
  for (int idx = t; idx < 4096; idx += 256) {
    int ni = idx >> 6, dj = idx & 63;
    T[ni][dj] = kvbf[((size_t)(b * 1024 + n0 + ni)) * 1024 + 512 + h * 64 + dj];
  }
  __syncthreads();
  for (int idx = t; idx < 4096; idx += 256) {
    int dj = idx >> 6, ni = idx & 63;
    vT[((size_t)(bh * 64 + dj)) * 1024 + n0 + ni] = T[ni][dj];
  }
}

// ---------------------------------------------------------------------------
// bf16 NT GEMM, BM=128 BN=64 BK=32, one-step register prefetch of the next
// K-tile issued before the MFMA block (hides HBM latency under compute).
__global__ __launch_bounds__(256) void gemm_nt64(const u16* __restrict__ A,
                                                 const u16* __restrict__ B,
                                                 void* __restrict__ Cout, int M, int N, int K,
                                                 int outBF) {
  __shared__ u16 As[128 * 40];
  __shared__ u16 Bs[64 * 40];
  int blk = blockIdx.x;
  int nblk = N >> 6;
  int m0 = (blk / nblk) << 7, n0 = (blk % nblk) << 6;
  int t = threadIdx.x;
  int lane = t & 63, w = t >> 6;
  int wr = w >> 1, wc = w & 1;
  int lr = lane & 15, kr = lane >> 4;

  v4f acc[4][2];
#pragma unroll
  for (int i = 0; i < 4; i++)
#pragma unroll
    for (int j = 0; j < 2; j++) acc[i][j] = (v4f){0.f, 0.f, 0.f, 0.f};

  const int r0 = t >> 2, s0 = (t & 3) * 8;
  const u16* Ap = &A[(size_t)(m0 + r0) * K + s0];
  const u16* Ap2 = &A[(size_t)(m0 + r0 + 64) * K + s0];
  const u16* Bp = &B[(size_t)(n0 + r0) * K + s0];

  int4 a0 = *(const int4*)Ap;
  int4 a1 = *(const int4*)Ap2;
  int4 b0 = *(const int4*)Bp;

  for (int k0 = 0; k0 < K; k0 += 32) {
    __syncthreads();
    *(int4*)&As[r0 * 40 + s0] = a0;
    *(int4*)&As[(r0 + 64) * 40 + s0] = a1;
    *(int4*)&Bs[r0 * 40 + s0] = b0;
    __syncthreads();
    if (k0 + 32 < K) {
      a0 = *(const int4*)(Ap + k0 + 32);
      a1 = *(const int4*)(Ap2 + k0 + 32);
      b0 = *(const int4*)(Bp + k0 + 32);
    }
    v8s af[4], bfr[2];
#pragma unroll
    for (int i = 0; i < 4; i++) af[i] = *(const v8s*)&As[(wr * 64 + i * 16 + lr) * 40 + kr * 8];
#pragma unroll
    for (int j = 0; j < 2; j++) bfr[j] = *(const v8s*)&Bs[(wc * 32 + j * 16 + lr) * 40 + kr * 8];
#pragma unroll
    for (int i = 0; i < 4; i++)
#pragma unroll
      for (int j = 0; j < 2; j++) acc[i][j] = MFMA16(af[i], bfr[j], acc[i][j]);
  }
#pragma unroll
  for (int i = 0; i < 4; i++)
#pragma unroll
    for (int j = 0; j < 2; j++) {
      int row = m0 + wr * 64 + i * 16 + kr * 4;
      int col = n0 + wc * 32 + j * 16 + lr;
#pragma unroll
      for (int q = 0; q < 4; q++) {
        float v = acc[i][j][q];
        if (outBF) ((u16*)Cout)[(size_t)(row + q) * N + col] = f2bf(v);
        else ((float*)Cout)[(size_t)(row + q) * N + col] = v;
      }
    }
}

// ---------------------------------------------------------------------------
// fused attention: per WG = (b, h, 16 q-rows).
//   Phase 1: S^T = (K q^T)/8 via swapped MFMA -> packed bf16 LDS rows.
//   Phase 2: per-row sequential dual top-k via binary search with SCALAR
//            counting (v_cmp + s_bcnt1 -> SGPR accumulation, uniform state);
//            no max-shift (|s|<~2 so exp safe); weights written in-place.
//   Phase 3: PV with per-wave d-slice (no cross-wave reduce, no opart LDS).
// LDS = Sb only (33.3 KB) -> 4 WGs/CU.
__global__ __launch_bounds__(256) void attn_kernel(
    const u16* __restrict__ qbf, const u16* __restrict__ kvbf, const u16* __restrict__ vT,
    u16* __restrict__ aobf, const float* __restrict__ kr1p, const float* __restrict__ kr2p) {
  __shared__ u16 Sb[16][1032];

  int blk = blockIdx.x;
  int xq = blk & 7, jq = blk >> 3;
  int bh = xq * 8 + (jq & 7);
  int rb = jq >> 3;
  int b = bh >> 3, h = bh & 7;
  int n0 = rb * 16;
  int t = threadIdx.x, lane = t & 63, w = t >> 6;
  int lr = lane & 15, kr = lane >> 4;

  float sg1 = 1.f / (1.f + __expf(-kr1p[0]));
  int k1 = min(max((int)(1024.f * sg1), 1), 1024);
  float sg2 = 1.f / (1.f + __expf(-kr2p[0]));
  int k2 = min(max((int)(1024.f * sg2), 1), 1024);

  {  // Phase 1: S^T tiles via mfma(K, Q); q fragments straight from global.
    const u16* qp = &qbf[(size_t)(b * 1024 + n0 + lr) * 512 + h * 64];
    v8s qf0 = *(const v8s*)&qp[kr * 8];
    v8s qf1 = *(const v8s*)&qp[32 + kr * 8];
    int cbase = w * 256;
#pragma unroll
    for (int cf = 0; cf < 16; cf++) {
      int c0 = cbase + cf * 16;
      const u16* kp = &kvbf[(size_t)(b * 1024 + c0 + lr) * 1024 + h * 64];
      v8s kf0 = *(const v8s*)&kp[kr * 8];
      v8s kf1 = *(const v8s*)&kp[32 + kr * 8];
      v4f acc = (v4f){0.f, 0.f, 0.f, 0.f};
      acc = MFMA16(kf0, qf0, acc);
      acc = MFMA16(kf1, qf1, acc);
      u32 p0 = (__float_as_uint(acc[0] * 0.125f) >> 16) |
               (__float_as_uint(acc[1] * 0.125f) & 0xffff0000u);
      u32 p1 = (__float_as_uint(acc[2] * 0.125f) >> 16) |
               (__float_as_uint(acc[3] * 0.125f) & 0xffff0000u);
      *(uint2*)&Sb[lr][c0 + kr * 4] = make_uint2(p0, p1);
    }
  }
  __syncthreads();

  {  // Phase 2: per-row sequential, scalar-state dual binary search
    int l = lane;
#pragma unroll 1
    for (int i = 0; i < 4; i++) {
      int rr = w * 4 + i;
      const u16* rowp = &Sb[rr][l * 16];
      uint4 r0 = *(const uint4*)rowp;
      uint4 r1 = *(const uint4*)(rowp + 8);
      u32 wdl[8] = {r0.x, r0.y, r0.z, r0.w, r1.x, r1.y, r1.z, r1.w};
      u32 key[16];
#pragma unroll
      for (int p = 0; p < 8; p++) {
        u32 m = (wdl[p] >> 15) & 0x10001u;
        u32 kp = wdl[p] ^ (0x80008000u ^ (m * 0x7fffu));
        key[2 * p] = kp & 0xffffu;
        key[2 * p + 1] = kp >> 16;
      }
      // dual binary search, all state scalar (SGPR); counts via v_cmp+s_bcnt1
      u32 lo1 = 0, hi1 = 65536, lo2 = 0, hi2 = 65536;
#pragma unroll 1
      for (int it = 0; it < 16; ++it) {
        u32 m1 = (lo1 + hi1) >> 1, m2 = (lo2 + hi2) >> 1;
        int c1 = 0, c2 = 0;
#pragma unroll
        for (int jj = 0; jj < 16; jj++) {
          c1 += cnt_ge(key[jj], m1);
          c2 += cnt_ge(key[jj], m2);
        }
        if (c1 >= k1) lo1 = m1; else hi1 = m1;
        if (c2 >= k2) lo2 = m2; else hi2 = m2;
      }
      u32 t1u = lo1, t2u = lo2;

      // masked softmax weights (exp computed once; no max-shift)
      float ev[16];
      float z1 = 0.f, z2 = 0.f;
#pragma unroll
      for (int jj = 0; jj < 16; jj++) {
        u16 s = (u16)(wdl[jj >> 1] >> ((jj & 1) * 16));
        float e = __expf(bf2f(s));
        ev[jj] = e;
        z1 += (key[jj] >= t1u) ? e : 0.f;
        z2 += (key[jj] >= t2u) ? e : 0.f;
      }
#pragma unroll
      for (int d = 1; d < 64; d <<= 1) {
        z1 += __shfl_xor(z1, d);
        z2 += __shfl_xor(z2, d);
      }
      float c1w = 0.6f / z1, c2w = 0.4f / z2;
      u32 ow[8];
#pragma unroll
      for (int p = 0; p < 8; p++) {
        float s0 = (key[2 * p] >= t1u) ? c1w : 0.f;
        s0 += (key[2 * p] >= t2u) ? c2w : 0.f;
        float s1 = (key[2 * p + 1] >= t1u) ? c1w : 0.f;
        s1 += (key[2 * p + 1] >= t2u) ? c2w : 0.f;
        u32 w0 = __float_as_uint(ev[2 * p] * s0);
        u32 w1 = __float_as_uint(ev[2 * p + 1] * s1);
        ow[p] = (w0 >> 16) | (w1 & 0xffff0000u);
      }
      *(uint4*)&Sb[rr][l * 16] = make_uint4(ow[0], ow[1], ow[2], ow[3]);
      *(uint4*)&Sb[rr][l * 16 + 8] = make_uint4(ow[4], ow[5], ow[6], ow[7]);
    }
  }
  __syncthreads();

  {  // Phase 3: PV, wave w owns d-slice [w*16, w*16+16) over the full context
    const u16* vrow = &vT[(size_t)(bh * 64 + w * 16 + lr) * 1024];
    v4f acc = (v4f){0.f, 0.f, 0.f, 0.f};
#pragma unroll
    for (int ks = 0; ks < 32; ks++) {
      int c0 = ks * 32;
      v8s a = *(const v8s*)&Sb[lr][c0 + kr * 8];
      v8s bb = *(const v8s*)&vrow[c0 + kr * 8];
      acc = MFMA16(a, bb, acc);
    }
#pragma unroll
    for (int j = 0; j < 4; j++)
      aobf[(size_t)(b * 1024 + n0 + kr * 4 + j) * 512 + h * 64 + w * 16 + lr] = f2bf(acc[j]);
  }
}

// ---------------------------------------------------------------------------
// final: out[b,c,n] = proj_gemm[(b,n),c] + proj_b[c] + x[b,c,n]
__global__ __launch_bounds__(256) void xpose_out(const float* __restrict__ G,
                                                 const float* __restrict__ x,
                                                 const float* __restrict__ pb,
                                                 float* __restrict__ out) {
  __shared__ float T[32][33];
  int blk = blockIdx.x;  // ((b*16 + cb)*32 + nb)
  int nb = blk & 31, cb = (blk >> 5) & 15, b = blk >> 9;
  int c0 = cb * 32, n0 = nb * 32;
  int t = threadIdx.x;
  for (int idx = t; idx < 1024; idx += 256) {
    int nj = idx >> 5, ci = idx & 31;
    T[ci][nj] = G[((size_t)(b * 1024 + n0 + nj)) * 512 + c0 + ci];
  }
  __syncthreads();
  for (int idx = t; idx < 1024; idx += 256) {
    int ci = idx >> 5, nj = idx & 31;
    size_t o = ((size_t)(b * 512 + c0 + ci)) * 1024 + n0 + nj;
    out[o] = T[ci][nj] + pb[c0 + ci] + x[o];
  }
}

// ---------------------------------------------------------------------------
extern "C" void kernel_launch(void* const* d_in, const int* in_sizes, int n_in,
                              void* d_out, int out_size, void* d_ws, size_t ws_size,
                              hipStream_t stream) {
  (void)in_sizes; (void)n_in; (void)out_size; (void)ws_size;
  const float* x = (const float*)d_in[0];
  const float* y = (const float*)d_in[1];
  const float* q_w = (const float*)d_in[2];
  const float* kv_w = (const float*)d_in[3];
  const float* proj_w = (const float*)d_in[4];
  const float* proj_b = (const float*)d_in[5];
  const float* c1w = (const float*)d_in[6];
  const float* c1b = (const float*)d_in[7];
  const float* c2w = (const float*)d_in[8];
  const float* c2b = (const float*)d_in[9];
  const float* c3w = (const float*)d_in[10];
  const float* c3b = (const float*)d_in[11];
  const float* ln_w = (const float*)d_in[12];
  const float* ln_b = (const float*)d_in[13];
  const float* kr1 = (const float*)d_in[14];
  const float* kr2 = (const float*)d_in[15];

  char* p = (char*)d_ws;
  auto alloc = [&](size_t bytes) {
    char* q = p;
    p += (bytes + 255) & ~(size_t)255;
    return q;
  };
  float* yf = (float*)alloc(8ull * 512 * 1024 * 4);      // 16 MB [B,C,N]
  u16* ynbf = (u16*)alloc(8192ull * 512 * 2);            // 8 MB  [B*N, C]
  u16* xsbf = (u16*)alloc(8192ull * 512 * 2);            // 8 MB  [B*N, C]
  u16* qwb = (u16*)alloc(512ull * 512 * 2);
  u16* kvwb = (u16*)alloc(1024ull * 512 * 2);
  u16* pwb = (u16*)alloc(512ull * 512 * 2);
  u16* qbf = (u16*)alloc(8192ull * 512 * 2);             // 8 MB
  u16* kvbf = (u16*)alloc(8192ull * 1024 * 2);           // 16 MB
  u16* vTb = (u16*)alloc(8ull * 8 * 64 * 1024 * 2);      // 8 MB [B,H,64,N]
  u16* aobf = (u16*)alloc(8192ull * 512 * 2);            // 8 MB
  float* projf = (float*)alloc(8192ull * 512 * 4);       // 16 MB

  cvt3<<<1024, 256, 0, stream>>>(q_w, qwb, 512 * 512, kv_w, kvwb, 1024 * 512, proj_w, pwb,
                                 512 * 512);
  conv_kernel<<<8 * 512, 256, 0, stream>>>(y, c1w, c1b, c2w, c2b, c3w, c3b, yf);
  ln_kernel<<<512, 256, 0, stream>>>(yf, ln_w, ln_b, ynbf);
  xpose_x<<<8 * 16 * 32, 256, 0, stream>>>(x, xsbf);
  gemm_nt64<<<64 * 8, 256, 0, stream>>>(xsbf, qwb, qbf, 8192, 512, 512, 1);
  gemm_nt64<<<64 * 16, 256, 0, stream>>>(ynbf, kvwb, kvbf, 8192, 1024, 512, 1);
  xpose_v<<<64 * 16, 256, 0, stream>>>(kvbf, vTb);
  attn_kernel<<<64 * 64, 256, 0, stream>>>(qbf, kvbf, vTb, aobf, kr1, kr2);
  gemm_nt64<<<64 * 8, 256, 0, stream>>>(aobf, pwb, projf, 8192, 512, 512, 0);
  xpose_out<<<8 * 16 * 32, 256, 0, stream>>>(projf, x, proj_b, (float*)d_out);
}